// Round 3
// baseline (584.917 us; speedup 1.0000x reference)
//
#include <hip/hip_runtime.h>

#define D 128
#define E_DIM 64

typedef float vf4 __attribute__((ext_vector_type(4)));
typedef float vf2 __attribute__((ext_vector_type(2)));

// ---------------------------------------------------------------------------
// Kernel 1: per-node score precompute.
// ns[n] = { h_n@Wu[:,0], h_n@Wu[:,1], h_n@Wv[:,0], h_n@Wv[:,1] }
// One 64-lane wave per node; each lane loads float2 of h (coalesced 512B/wave)
// ---------------------------------------------------------------------------
__global__ void node_score_kernel(const float* __restrict__ node_feats,
                                  const float* __restrict__ W,
                                  vf4* __restrict__ ns,
                                  int n_nodes) {
    int wave = (blockIdx.x * blockDim.x + threadIdx.x) >> 6;
    int lane = threadIdx.x & 63;
    if (wave >= n_nodes) return;

    const vf2 h = ((const vf2*)(node_feats + (size_t)wave * D))[lane];
    const int r0 = lane * 2;
    const int r1 = lane * 2 + 1;
    // W is (2*D + E_DIM, 2) row-major; Wu rows [0,128), Wv rows [128,256)
    float p0 = h.x * W[r0 * 2 + 0]       + h.y * W[r1 * 2 + 0];
    float p1 = h.x * W[r0 * 2 + 1]       + h.y * W[r1 * 2 + 1];
    float p2 = h.x * W[(D + r0) * 2 + 0] + h.y * W[(D + r1) * 2 + 0];
    float p3 = h.x * W[(D + r0) * 2 + 1] + h.y * W[(D + r1) * 2 + 1];

    for (int off = 32; off > 0; off >>= 1) {
        p0 += __shfl_down(p0, off, 64);
        p1 += __shfl_down(p1, off, 64);
        p2 += __shfl_down(p2, off, 64);
        p3 += __shfl_down(p3, off, 64);
    }
    if (lane == 0) {
        vf4 v; v.x = p0; v.y = p1; v.z = p2; v.w = p3;
        ns[wave] = v;
    }
}

// ---------------------------------------------------------------------------
// Kernel 2: per-edge. 16 lanes per edge; each lane loads one nontemporal
// float4 of edge_feats (wave covers 4 edges = 1 KiB contiguous).
// Gathers (src/dst/ns) are issued by ALL lanes of the group (same address ->
// single broadcast transaction, no divergence) BEFORE the dot product, so
// their L2 latency overlaps the FMA + shuffle-reduce work.
// ---------------------------------------------------------------------------
__global__ void __launch_bounds__(256) edge_score_kernel(
        const float* __restrict__ edge_feats,
        const int* __restrict__ src,
        const int* __restrict__ dst,
        const float* __restrict__ W,
        const float* __restrict__ b,
        const vf4* __restrict__ ns,
        float* __restrict__ out,
        int n_edges) {
    int tid = blockIdx.x * blockDim.x + threadIdx.x;
    int e = tid >> 4;
    int l = tid & 15;
    if (e >= n_edges) return;

    // Early gathers — same address across the 16-lane group => broadcast.
    const int   si = src[e];
    const int   di = dst[e];
    const vf4 sv = ns[si];            // .x,.y = h_src@Wu
    const vf4 dv = ns[di];            // .z,.w = h_dst@Wv
    const float b0 = b[0];
    const float b1 = b[1];

    const vf4 ef = __builtin_nontemporal_load(
        (const vf4*)edge_feats + (size_t)e * (E_DIM / 4) + l);

    const int r = 2 * D + l * 4;   // We rows [256, 320)
    float p0 = ef.x * W[(r + 0) * 2 + 0] + ef.y * W[(r + 1) * 2 + 0]
             + ef.z * W[(r + 2) * 2 + 0] + ef.w * W[(r + 3) * 2 + 0];
    float p1 = ef.x * W[(r + 0) * 2 + 1] + ef.y * W[(r + 1) * 2 + 1]
             + ef.z * W[(r + 2) * 2 + 1] + ef.w * W[(r + 3) * 2 + 1];

    for (int m = 8; m > 0; m >>= 1) {
        p0 += __shfl_xor(p0, m, 16);
        p1 += __shfl_xor(p1, m, 16);
    }

    if (l == 0) {
        vf2 o;
        o.x = p0 + sv.x + dv.z + b0;
        o.y = p1 + sv.y + dv.w + b1;
        __builtin_nontemporal_store(o, (vf2*)out + e);
    }
}

// ---------------------------------------------------------------------------
// Fallback (only if ws_size is too small for the 800 KB node-score table):
// one wave per edge, full gather of both node rows + edge row, 64-lane reduce.
// ---------------------------------------------------------------------------
__global__ void edge_fallback_kernel(const float* __restrict__ node_feats,
                                     const float* __restrict__ edge_feats,
                                     const int* __restrict__ src,
                                     const int* __restrict__ dst,
                                     const float* __restrict__ W,
                                     const float* __restrict__ b,
                                     float* __restrict__ out,
                                     int n_edges) {
    int wave = (blockIdx.x * blockDim.x + threadIdx.x) >> 6;
    int l = threadIdx.x & 63;
    if (wave >= n_edges) return;

    const float* hu = node_feats + (size_t)src[wave] * D;
    const float* hv = node_feats + (size_t)dst[wave] * D;
    const float u0 = hu[l], u1 = hu[l + 64];
    const float v0 = hv[l], v1 = hv[l + 64];
    const float e0 = edge_feats[(size_t)wave * E_DIM + l];

    float p0 = u0 * W[l * 2 + 0]         + u1 * W[(l + 64) * 2 + 0]
             + v0 * W[(128 + l) * 2 + 0] + v1 * W[(192 + l) * 2 + 0]
             + e0 * W[(256 + l) * 2 + 0];
    float p1 = u0 * W[l * 2 + 1]         + u1 * W[(l + 64) * 2 + 1]
             + v0 * W[(128 + l) * 2 + 1] + v1 * W[(192 + l) * 2 + 1]
             + e0 * W[(256 + l) * 2 + 1];

    for (int off = 32; off > 0; off >>= 1) {
        p0 += __shfl_down(p0, off, 64);
        p1 += __shfl_down(p1, off, 64);
    }
    if (l == 0) {
        vf2 o;
        o.x = p0 + b[0];
        o.y = p1 + b[1];
        ((vf2*)out)[wave] = o;
    }
}

extern "C" void kernel_launch(void* const* d_in, const int* in_sizes, int n_in,
                              void* d_out, int out_size, void* d_ws, size_t ws_size,
                              hipStream_t stream) {
    const float* node_feats = (const float*)d_in[0];
    const float* edge_feats = (const float*)d_in[1];
    const int*   src        = (const int*)d_in[2];
    const int*   dst        = (const int*)d_in[3];
    const float* W          = (const float*)d_in[4];
    const float* b          = (const float*)d_in[5];
    float*       out        = (float*)d_out;

    const int n_nodes = in_sizes[0] / D;
    const int n_edges = in_sizes[2];

    const size_t ns_bytes = (size_t)n_nodes * 4 * sizeof(float);

    if (ws_size >= ns_bytes) {
        vf4* ns = (vf4*)d_ws;
        // 4 nodes per 256-thread block (one wave each)
        int nblk1 = (n_nodes + 3) / 4;
        node_score_kernel<<<nblk1, 256, 0, stream>>>(node_feats, W, ns, n_nodes);
        // 16 edges per 256-thread block (16 lanes each)
        int nblk2 = (n_edges + 15) / 16;
        edge_score_kernel<<<nblk2, 256, 0, stream>>>(edge_feats, src, dst, W, b,
                                                     ns, out, n_edges);
    } else {
        // 4 edges per 256-thread block (one wave each)
        int nblk = (n_edges + 3) / 4;
        edge_fallback_kernel<<<nblk, 256, 0, stream>>>(node_feats, edge_feats,
                                                       src, dst, W, b, out, n_edges);
    }
}